// Round 15
// baseline (330.711 us; speedup 1.0000x reference)
//
#include <hip/hip_runtime.h>
#include <hip/hip_bf16.h>
#include <stdint.h>

#define BB 8
#define NN 2048
#define DD 1024
#define HH 1024

using f32x4 = __attribute__((ext_vector_type(4))) float;
using s16x8 = __attribute__((ext_vector_type(8))) short;

__device__ __forceinline__ short f2bf(float f){
  union { float f; uint32_t u; } v; v.f = f;
  uint32_t r = (v.u + 0x7fffu + ((v.u >> 16) & 1u)) >> 16;
  return (short)r;
}
__device__ __forceinline__ float bf2f(short s){
  union { uint32_t u; float f; } v; v.u = ((uint32_t)(uint16_t)s) << 16; return v.f;
}

#define MFMA(a,b,c) __builtin_amdgcn_mfma_f32_16x16x32_bf16((a),(b),(c),0,0,0)

// async global->LDS, 16B per lane. LDS dest is wave-uniform base + lane*16.
#define GL16(gp, lp) __builtin_amdgcn_global_load_lds( \
    (const __attribute__((address_space(1))) void*)(gp), \
    (__attribute__((address_space(3))) void*)(lp), 16, 0, 0)

// ---------------- kernel 0a: x fp32 -> bf16 ----------------
__global__ __launch_bounds__(256) void k_conv_x(const float* __restrict__ x,
                                                short* __restrict__ xb){
  int gid = blockIdx.x*256 + threadIdx.x;
  const float4* xv = (const float4*)x;
  float4 a = xv[(size_t)gid*2], b2 = xv[(size_t)gid*2+1];
  s16x8 o;
  o[0]=f2bf(a.x);  o[1]=f2bf(a.y);  o[2]=f2bf(a.z);  o[3]=f2bf(a.w);
  o[4]=f2bf(b2.x); o[5]=f2bf(b2.y); o[6]=f2bf(b2.z); o[7]=f2bf(b2.w);
  *(s16x8*)(xb + (size_t)gid*8) = o;
}

// ---------------- kernel 0b: pack W^T bf16 [3072][1024] ----------------
__global__ __launch_bounds__(256) void k_conv_w(const float* __restrict__ Wq,
                                                const float* __restrict__ Wk,
                                                const float* __restrict__ Wv,
                                                short* __restrict__ Wt){
  __shared__ float tile[64][65];
  int bx = blockIdx.x; int mat = bx >> 8; int ti = bx & 255;
  int d0 = (ti >> 4) << 6, h0 = (ti & 15) << 6;
  const float* W = (mat==0) ? Wq : (mat==1 ? Wk : Wv);
  int t = threadIdx.x;
  for (int i=0;i<16;i++){ int e = i*256 + t; int r = e>>6, c = e&63;
    tile[r][c] = W[(size_t)(d0+r)*HH + h0 + c]; }
  __syncthreads();
  for (int i=0;i<16;i++){ int e = i*256 + t; int r = e>>6, c = e&63;
    Wt[(size_t)(mat*HH + h0 + r)*DD + d0 + c] = f2bf(tile[c][r]); }
}

// ---------------- kernel 1: QKV GEMM — A via rolling 4-slot LDS, B DIRECT ------
// Diagnosis: previous structure was LDS-read-throughput bound (24 b128/wave/tile
// -> 2304 cy/CU/tile > 1242 cy MFMA floor). Fix: B fragments read directly
// global->register (B panel is L2-resident, shared by 64 blocks per column),
// one-slot-ahead register prefetch (static bfrE/bfrO names). LDS reads halve
// to 16 b128/wave/tile (1536 cy). A keeps the proven rolling 4-slot pipeline.
// vmcnt ledger (F=4 B-loads + S=2 A-stages per body): steady vmcnt(2);
// vmcnt(4) at kt=0; vmcnt(0) for last 2 bodies. LDS = 64 KB (A only).
__global__ __launch_bounds__(512,2) void k_gemm(const short* __restrict__ Aw,
                                                const short* __restrict__ Bw,
                                                const float* __restrict__ bq,
                                                const float* __restrict__ bk,
                                                const float* __restrict__ bv,
                                                short* __restrict__ Qw,
                                                short* __restrict__ Kw,
                                                short* __restrict__ Vt){
  __shared__ short Al[4][256*32];                  // 64 KB
  const int t = threadIdx.x, l = t & 63, w = t >> 6;
  const int g = l >> 4, c = l & 15;
  const int bid = blockIdx.x;
  const int bm = (bid & 7)*8 + ((bid >> 3) & 7);   // 0..63
  const int bn = bid >> 6;                          // 0..11
  const int m0 = bm << 8, c0 = bn << 8;
  const int wr = w >> 2, wc = w & 3;
  f32x4 acc[8][4] = {};

  // A staging: thread t covers rows (t>>2), (t>>2)+128, chunk t&3 (16B).
  const int sr = t >> 2, sch = t & 3;
  const int u0 = sch ^ ((sr >> 1) & 3);
  const int u1 = sch ^ (((sr + 128) >> 1) & 3);
  const short* A0 = Aw + (size_t)(m0 + sr)*DD + u0*8;
  const short* A1 = Aw + (size_t)(m0 + sr + 128)*DD + u1*8;
  const int d0b = sr*64 + sch*16, d1b = (sr+128)*64 + sch*16;
  auto stageA = [&](int kt){
    int s = kt & 3, ko = kt*32;
    GL16(A0 + ko, (char*)&Al[s][0] + d0b);
    GL16(A1 + ko, (char*)&Al[s][0] + d1b);
  };

  int aoff[8];
  #pragma unroll
  for (int mi=0;mi<8;mi++){
    int row = wr*128 + mi*16 + c;
    aoff[mi] = row*32 + (g ^ ((row>>1)&3))*8;
  }
  // B direct: fragment row ptrs (lane: row = c0 + wc*64 + ni*16 + c, col g*8)
  const short* Bp[4];
  #pragma unroll
  for (int ni=0;ni<4;ni++)
    Bp[ni] = Bw + (size_t)(c0 + wc*64 + ni*16 + c)*DD + g*8;

  s16x8 bfrE[4], bfrO[4];

  auto body = [&](int kt, s16x8 (&cur)[4], s16x8 (&nxt)[4]){
    if (kt == 0)      { asm volatile("s_waitcnt vmcnt(4)" ::: "memory"); }
    else if (kt < 30) { asm volatile("s_waitcnt vmcnt(2)" ::: "memory"); }
    else              { asm volatile("s_waitcnt vmcnt(0)" ::: "memory"); }
    __builtin_amdgcn_sched_barrier(0);
    __builtin_amdgcn_s_barrier();
    __builtin_amdgcn_sched_barrier(0);
    const int s = kt & 3;
    s16x8 af[8];
    #pragma unroll
    for (int mi=0;mi<8;mi++) af[mi] = *(const s16x8*)&Al[s][aoff[mi]];
    if (kt < 31){
      const int ko = (kt+1)*32;
      #pragma unroll
      for (int ni=0;ni<4;ni++) nxt[ni] = *(const s16x8*)(Bp[ni] + ko);
    }
    if (kt < 29) stageA(kt+3);
    __builtin_amdgcn_sched_barrier(0);
    __builtin_amdgcn_s_setprio(1);
    #pragma unroll
    for (int mi=0;mi<8;mi++)
      #pragma unroll
      for (int ni=0;ni<4;ni++)
        acc[mi][ni] = MFMA(cur[ni], af[mi], acc[mi][ni]);
    __builtin_amdgcn_s_setprio(0);
  };

  // prologue: F0 (4 loads), then S0,S1,S2 (6 loads)
  #pragma unroll
  for (int ni=0;ni<4;ni++) bfrE[ni] = *(const s16x8*)(Bp[ni]);
  stageA(0); stageA(1); stageA(2);

  for (int k2 = 0; k2 < 16; ++k2){
    body(2*k2,     bfrE, bfrO);
    body(2*k2 + 1, bfrO, bfrE);
  }

  const int mat = bn >> 2;
  const float* bias = (mat==0) ? bq : (mat==1 ? bk : bv);
  if (mat < 2){
    short* Outp = (mat==0) ? Qw : Kw;
    #pragma unroll
    for (int ni=0;ni<4;ni++){
      int col0 = (bn & 3)*256 + wc*64 + ni*16 + g*4;
      float4 bv4 = *(const float4*)&bias[col0];
      #pragma unroll
      for (int mi=0;mi<8;mi++){
        int orow = m0 + wr*128 + mi*16 + c;
        short4 pk;
        pk.x = f2bf(acc[mi][ni][0] + bv4.x);
        pk.y = f2bf(acc[mi][ni][1] + bv4.y);
        pk.z = f2bf(acc[mi][ni][2] + bv4.z);
        pk.w = f2bf(acc[mi][ni][3] + bv4.w);
        *(short4*)&Outp[(size_t)orow*HH + col0] = pk;
      }
    }
  } else {
    // V: per-wave LDS transpose into Vt[b][h][n]. Scratch: wave w -> 8 KB at
    // Al + w*4096 shorts ([64][64]). Barrier first: other waves may still be
    // reading slot 3 in body(31).
    __syncthreads();
    short* S = (short*)&Al[0][0] + w*4096;
    const int bb = m0 >> 11;
    const int nbase = m0 & 2047;
    const int hglob0 = (bn & 3)*256 + wc*64;
    #pragma unroll
    for (int rr = 0; rr < 2; ++rr){
      const int R = 2*wr + rr;
      asm volatile("" ::: "memory");
      #pragma unroll
      for (int ni=0;ni<4;ni++){
        int col0 = hglob0 + ni*16 + g*4;
        float4 bv4 = *(const float4*)&bias[col0];
        #pragma unroll
        for (int mi2=0;mi2<4;mi2++){
          short4 pk;
          pk.x = f2bf(acc[rr*4+mi2][ni][0] + bv4.x);
          pk.y = f2bf(acc[rr*4+mi2][ni][1] + bv4.y);
          pk.z = f2bf(acc[rr*4+mi2][ni][2] + bv4.z);
          pk.w = f2bf(acc[rr*4+mi2][ni][3] + bv4.w);
          *(short4*)&S[(mi2*16 + c)*64 + ni*16 + g*4] = pk;
        }
      }
      asm volatile("" ::: "memory");
      #pragma unroll
      for (int k=0;k<8;++k){
        int hr = (l>>3) + k*8;
        int ng = l & 7;
        s16x8 sv;
        #pragma unroll
        for (int e=0;e<8;e++) sv[e] = S[(ng*8+e)*64 + hr];
        *(s16x8*)&Vt[((size_t)bb*HH + hglob0 + hr)*NN + nbase + R*64 + ng*8] = sv;
      }
      asm volatile("" ::: "memory");
      __syncthreads();     // wave scratch reused across rr; keep block in step
    }
  }
}

// ---------------- kernel 2: P = exp2(Q K^T * scale*log2e), 128x256 strips ------
// 512 threads = 8 waves (2q x 4k). Single-buffer 24 KiB, 2-barrier structure
// (high occupancy, cross-block overlap). Strips packed at cum(tr)=(tr+1)^2/4;
// masked cols store P=0. 576 blocks, uniform 32 steps each.
__global__ __launch_bounds__(512) void k_s(const short* __restrict__ Qw,
                                           const short* __restrict__ Kw,
                                           short* __restrict__ Pp){
  __shared__ short Ql[128*32];
  __shared__ short Kl[256*32];
  const int t = threadIdx.x, l = t & 63, w = t >> 6;
  const int g = l >> 4, c = l & 15;
  int p = blockIdx.x; int b = p & 7; int si = p >> 3;       // strip 0..71
  int tr = 0; while ((((tr+2)*(tr+2)) >> 2) <= si) tr++;
  int tcp = si - (((tr+1)*(tr+1)) >> 2);
  const float SC_EXP = 0.04508422002783268f;   // (1/32) * log2(e)
  const int wq = w >> 2, wk = w & 3;
  f32x4 acc[4][4] = {};

  const int sr = t >> 2, sch = t & 3;
  const int su  = sch ^ ((sr >> 1) & 3);
  const int su2 = sch ^ (((sr + 128) >> 1) & 3);
  const short* Qs  = Qw + ((size_t)(b*NN + tr*128  + sr))*HH + su*8;
  const short* Ks0 = Kw + ((size_t)(b*NN + tcp*256 + sr))*HH + su*8;
  const short* Ks1 = Kw + ((size_t)(b*NN + tcp*256 + sr + 128))*HH + su2*8;

  const int rchunk = (g ^ ((c>>1)&3)) * 8;
  int qoff[4], koff[4];
  #pragma unroll
  for (int mi=0;mi<4;mi++) qoff[mi] = (wq*64 + mi*16 + c)*32 + rchunk;
  #pragma unroll
  for (int ni=0;ni<4;ni++) koff[ni] = (wk*64 + ni*16 + c)*32 + rchunk;

  for (int kt = 0; kt < 32; ++kt){
    int ko = kt*32;
    __syncthreads();
    GL16(Qs  + ko, (char*)Ql + t*16);
    GL16(Ks0 + ko, (char*)Kl + t*16);
    GL16(Ks1 + ko, (char*)Kl + 8192 + t*16);
    __syncthreads();
    s16x8 qf[4], kf[4];
    #pragma unroll
    for (int ni=0;ni<4;ni++) kf[ni] = *(const s16x8*)&Kl[koff[ni]];
    #pragma unroll
    for (int mi=0;mi<4;mi++) qf[mi] = *(const s16x8*)&Ql[qoff[mi]];
    #pragma unroll
    for (int mi=0;mi<4;mi++)
      #pragma unroll
      for (int ni=0;ni<4;ni++)
        acc[mi][ni] = MFMA(kf[ni], qf[mi], acc[mi][ni]);
  }

  short* Pt = Pp + ((size_t)(b*72 + si))*32768;    // strip: [128][256] bf16
  #pragma unroll
  for (int ni=0;ni<4;ni++){
    int pc0 = wk*64 + ni*16 + g*4;
    #pragma unroll
    for (int mi=0;mi<4;mi++){
      int pr = wq*64 + mi*16 + c;
      short4 pk;
      #pragma unroll
      for (int i=0;i<4;i++){
        bool keep = (tcp*256 + pc0 + i) <= (tr*128 + pr);
        float pv = keep ? exp2f(acc[mi][ni][i]*SC_EXP) : 0.f;
        ((short*)&pk)[i] = f2bf(pv);
      }
      *(short4*)&Pt[pr*256 + pc0] = pk;
    }
  }
}

// ---------------- kernel 3: O = (P V) / rowsum(P), 128x256 output tiles --------
// 512 threads = 8 waves (2q x 4h). 512 blocks, 2 rounds pairing tr with 15-tr.
// Single-buffer 24 KiB, 2-barrier structure. float4 stores.
__global__ __launch_bounds__(512) void k_pv(const short* __restrict__ Pp,
                                            const short* __restrict__ Vt,
                                            float* __restrict__ out){
  __shared__ short Pl[128*32];
  __shared__ short Vl[256*32];
  const int t = threadIdx.x, l = t & 63, w = t >> 6;
  const int g = l >> 4, c = l & 15;
  int p = blockIdx.x;
  int r = p >> 8, j = p & 255;
  int tr = r ? (15 - (j >> 4)) : (j >> 4);
  int id = r ? (16 + (j & 15)) : (j & 15);     // 32 ids: b(3b) | hc(2b)
  int b = id & 7, hc = id >> 3;                // hc 0..3
  const short* Pb = Pp + ((size_t)(b*72 + (((tr+1)*(tr+1))>>2)))*32768;
  const int wq = w >> 2, wh = w & 3;
  f32x4 acc[4][4] = {};
  float ls[4] = {0.f,0.f,0.f,0.f};

  const int sr = t >> 2, sch = t & 3;
  const int su  = sch ^ ((sr >> 1) & 3);
  const int su2 = sch ^ (((sr + 128) >> 1) & 3);
  const short* Vs0 = Vt + ((size_t)(b*HH + hc*256 + sr))*NN + su*8;
  const short* Vs1 = Vt + ((size_t)(b*HH + hc*256 + sr + 128))*NN + su2*8;

  const int rchunk = (g ^ ((c>>1)&3)) * 8;
  int poff[4], voff[4];
  #pragma unroll
  for (int mi=0;mi<4;mi++) poff[mi] = (wq*64 + mi*16 + c)*32 + rchunk;
  #pragma unroll
  for (int ni=0;ni<4;ni++) voff[ni] = (wh*64 + ni*16 + c)*32 + rchunk;

  const int nst = ((tr + 2) >> 1) * 8;         // strips * 8 steps
  for (int kt = 0; kt < nst; ++kt){
    const short* Ps = Pb + (size_t)(kt>>3)*32768 + (kt&7)*32;
    __syncthreads();
    GL16(Ps + sr*256 + su*8, (char*)Pl + t*16);
    GL16(Vs0 + kt*32, (char*)Vl + t*16);
    GL16(Vs1 + kt*32, (char*)Vl + 8192 + t*16);
    __syncthreads();
    s16x8 pf[4], vf[4];
    #pragma unroll
    for (int ni=0;ni<4;ni++) vf[ni] = *(const s16x8*)&Vl[voff[ni]];
    #pragma unroll
    for (int mi=0;mi<4;mi++) pf[mi] = *(const s16x8*)&Pl[poff[mi]];
    #pragma unroll
    for (int mi=0;mi<4;mi++){
      #pragma unroll
      for (int e=0;e<8;e++) ls[mi] += bf2f(pf[mi][e]);   // row-sum of P
    }
    #pragma unroll
    for (int mi=0;mi<4;mi++)
      #pragma unroll
      for (int ni=0;ni<4;ni++)
        acc[mi][ni] = MFMA(vf[ni], pf[mi], acc[mi][ni]);
  }
  #pragma unroll
  for (int mi=0;mi<4;mi++){
    ls[mi] += __shfl_xor(ls[mi], 16);
    ls[mi] += __shfl_xor(ls[mi], 32);    // full row-sum; lane row = wq*64+mi*16+c
  }
  #pragma unroll
  for (int mi=0;mi<4;mi++){
    float linv = 1.0f / ls[mi];
    int orow = tr*128 + wq*64 + mi*16 + c;
    #pragma unroll
    for (int ni=0;ni<4;ni++){
      int h0 = hc*256 + wh*64 + ni*16 + g*4;
      float4 o4;
      o4.x = acc[mi][ni][0]*linv; o4.y = acc[mi][ni][1]*linv;
      o4.z = acc[mi][ni][2]*linv; o4.w = acc[mi][ni][3]*linv;
      *(float4*)&out[((size_t)(b*NN + orow))*HH + h0] = o4;
    }
  }
}

extern "C" void kernel_launch(void* const* d_in, const int* in_sizes, int n_in,
                              void* d_out, int out_size, void* d_ws, size_t ws_size,
                              hipStream_t stream) {
  const float* x  = (const float*)d_in[0];
  const float* Wq = (const float*)d_in[1];
  const float* bq = (const float*)d_in[2];
  const float* Wk = (const float*)d_in[3];
  const float* bk = (const float*)d_in[4];
  const float* Wv = (const float*)d_in[5];
  const float* bv = (const float*)d_in[6];
  char* ws = (char*)d_ws;
  // ws layout (bytes). Pp (37.75 MB) OVERLAYS xb+Wt (both dead after k_gemm).
  short* xb = (short*)(ws);                         // 33,554,432
  short* Pp = (short*)(ws);                         // 37,748,736 (overlay)
  short* Wt = (short*)(ws + 33554432u);             //  6,291,456
  short* Qw = (short*)(ws + 41943040u);             // 33,554,432
  short* Kw = (short*)(ws + 75497472u);             // 33,554,432
  short* Vt = (short*)(ws + 109051904u);            // 33,554,432

  k_conv_x<<<8192, 256, 0, stream>>>(x, xb);
  k_conv_w<<<768, 256, 0, stream>>>(Wq, Wk, Wv, Wt);
  k_gemm<<<768, 512, 0, stream>>>(xb, Wt, bq, bk, bv, Qw, Kw, Vt);
  k_s<<<576, 512, 0, stream>>>(Qw, Kw, Pp);
  k_pv<<<512, 512, 0, stream>>>(Pp, Vt, (float*)d_out);
}

// Round 16
// 280.676 us; speedup vs baseline: 1.1783x; 1.1783x over previous
//
#include <hip/hip_runtime.h>
#include <hip/hip_bf16.h>
#include <stdint.h>

#define BB 8
#define NN 2048
#define DD 1024
#define HH 1024

using f32x4 = __attribute__((ext_vector_type(4))) float;
using s16x8 = __attribute__((ext_vector_type(8))) short;

__device__ __forceinline__ short f2bf(float f){
  union { float f; uint32_t u; } v; v.f = f;
  uint32_t r = (v.u + 0x7fffu + ((v.u >> 16) & 1u)) >> 16;
  return (short)r;
}
__device__ __forceinline__ float bf2f(short s){
  union { uint32_t u; float f; } v; v.u = ((uint32_t)(uint16_t)s) << 16; return v.f;
}

#define MFMA(a,b,c) __builtin_amdgcn_mfma_f32_16x16x32_bf16((a),(b),(c),0,0,0)

// async global->LDS, 16B per lane. LDS dest is wave-uniform base + lane*16.
#define GL16(gp, lp) __builtin_amdgcn_global_load_lds( \
    (const __attribute__((address_space(1))) void*)(gp), \
    (__attribute__((address_space(3))) void*)(lp), 16, 0, 0)

// ---------------- kernel 0a: x fp32 -> bf16 ----------------
__global__ __launch_bounds__(256) void k_conv_x(const float* __restrict__ x,
                                                short* __restrict__ xb){
  int gid = blockIdx.x*256 + threadIdx.x;
  const float4* xv = (const float4*)x;
  float4 a = xv[(size_t)gid*2], b2 = xv[(size_t)gid*2+1];
  s16x8 o;
  o[0]=f2bf(a.x);  o[1]=f2bf(a.y);  o[2]=f2bf(a.z);  o[3]=f2bf(a.w);
  o[4]=f2bf(b2.x); o[5]=f2bf(b2.y); o[6]=f2bf(b2.z); o[7]=f2bf(b2.w);
  *(s16x8*)(xb + (size_t)gid*8) = o;
}

// ---------------- kernel 0b: pack W^T bf16 [3072][1024] ----------------
__global__ __launch_bounds__(256) void k_conv_w(const float* __restrict__ Wq,
                                                const float* __restrict__ Wk,
                                                const float* __restrict__ Wv,
                                                short* __restrict__ Wt){
  __shared__ float tile[64][65];
  int bx = blockIdx.x; int mat = bx >> 8; int ti = bx & 255;
  int d0 = (ti >> 4) << 6, h0 = (ti & 15) << 6;
  const float* W = (mat==0) ? Wq : (mat==1 ? Wk : Wv);
  int t = threadIdx.x;
  for (int i=0;i<16;i++){ int e = i*256 + t; int r = e>>6, c = e&63;
    tile[r][c] = W[(size_t)(d0+r)*HH + h0 + c]; }
  __syncthreads();
  for (int i=0;i<16;i++){ int e = i*256 + t; int r = e>>6, c = e&63;
    Wt[(size_t)(mat*HH + h0 + r)*DD + d0 + c] = f2bf(tile[c][r]); }
}

// ---------------- kernel 1: QKV GEMM, rolling 4-slot BK=32 pipeline ------------
// R12/R14-proven form (903 TF — the non-fine-interleave structural ceiling,
// confirmed across 6 structural variants R5-R15).
// V-blocks (bn>=8) write Vt[b][h][n] directly via per-wave LDS transpose.
__global__ __launch_bounds__(512,2) void k_gemm(const short* __restrict__ Aw,
                                                const short* __restrict__ Bw,
                                                const float* __restrict__ bq,
                                                const float* __restrict__ bk,
                                                const float* __restrict__ bv,
                                                short* __restrict__ Qw,
                                                short* __restrict__ Kw,
                                                short* __restrict__ Vt){
  __shared__ short Al[4][256*32];
  __shared__ short Bl[4][256*32];
  const int t = threadIdx.x, l = t & 63, w = t >> 6;
  const int g = l >> 4, c = l & 15;
  const int bid = blockIdx.x;
  const int bm = (bid & 7)*8 + ((bid >> 3) & 7);   // 0..63
  const int bn = bid >> 6;                          // 0..11
  const int m0 = bm << 8, c0 = bn << 8;
  const int wr = w >> 2, wc = w & 3;
  f32x4 acc[8][4] = {};

  const int sr = t >> 2, sch = t & 3;
  const int u0 = sch ^ ((sr >> 1) & 3);
  const int u1 = sch ^ (((sr + 128) >> 1) & 3);
  const short* A0 = Aw + (size_t)(m0 + sr)*DD + u0*8;
  const short* A1 = Aw + (size_t)(m0 + sr + 128)*DD + u1*8;
  const short* B0 = Bw + (size_t)(c0 + sr)*DD + u0*8;
  const short* B1 = Bw + (size_t)(c0 + sr + 128)*DD + u1*8;
  const int d0b = sr*64 + sch*16, d1b = (sr+128)*64 + sch*16;
  auto stage = [&](int kt){
    int s = kt & 3, ko = kt*32;
    GL16(A0 + ko, (char*)&Al[s][0] + d0b);
    GL16(A1 + ko, (char*)&Al[s][0] + d1b);
    GL16(B0 + ko, (char*)&Bl[s][0] + d0b);
    GL16(B1 + ko, (char*)&Bl[s][0] + d1b);
  };

  int aoff[8], boff[4];
  #pragma unroll
  for (int mi=0;mi<8;mi++){
    int row = wr*128 + mi*16 + c;
    aoff[mi] = row*32 + (g ^ ((row>>1)&3))*8;
  }
  #pragma unroll
  for (int ni=0;ni<4;ni++){
    int row = wc*64 + ni*16 + c;
    boff[ni] = row*32 + (g ^ ((row>>1)&3))*8;
  }

  auto body = [&](int kt, bool dostage){
    int s = kt & 3;
    __builtin_amdgcn_sched_barrier(0);
    __builtin_amdgcn_s_barrier();
    __builtin_amdgcn_sched_barrier(0);
    s16x8 bfr[4], af[8];
    #pragma unroll
    for (int ni=0;ni<4;ni++) bfr[ni] = *(const s16x8*)&Bl[s][boff[ni]];
    #pragma unroll
    for (int mi=0;mi<8;mi++) af[mi] = *(const s16x8*)&Al[s][aoff[mi]];
    if (dostage) stage(kt+3);
    __builtin_amdgcn_s_setprio(1);
    #pragma unroll
    for (int mi=0;mi<8;mi++)
      #pragma unroll
      for (int ni=0;ni<4;ni++)
        acc[mi][ni] = MFMA(bfr[ni], af[mi], acc[mi][ni]);
    __builtin_amdgcn_s_setprio(0);
  };

  stage(0); stage(1); stage(2);
  for (int kt = 0; kt < 30; ++kt){
    asm volatile("s_waitcnt vmcnt(8)" ::: "memory");
    body(kt, kt < 29);
  }
  asm volatile("s_waitcnt vmcnt(4)" ::: "memory");
  body(30, false);
  asm volatile("s_waitcnt vmcnt(0)" ::: "memory");
  body(31, false);

  const int mat = bn >> 2;
  const float* bias = (mat==0) ? bq : (mat==1 ? bk : bv);
  if (mat < 2){
    short* Outp = (mat==0) ? Qw : Kw;
    #pragma unroll
    for (int ni=0;ni<4;ni++){
      int col0 = (bn & 3)*256 + wc*64 + ni*16 + g*4;
      float4 bv4 = *(const float4*)&bias[col0];
      #pragma unroll
      for (int mi=0;mi<8;mi++){
        int orow = m0 + wr*128 + mi*16 + c;
        short4 pk;
        pk.x = f2bf(acc[mi][ni][0] + bv4.x);
        pk.y = f2bf(acc[mi][ni][1] + bv4.y);
        pk.z = f2bf(acc[mi][ni][2] + bv4.z);
        pk.w = f2bf(acc[mi][ni][3] + bv4.w);
        *(short4*)&Outp[(size_t)orow*HH + col0] = pk;
      }
    }
  } else {
    // V: per-wave LDS transpose into Vt[b][h][n].
    short* S = (w < 4) ? ((short*)&Al[0][0] + w*4352)
                       : ((short*)&Bl[0][0] + (w-4)*4352);
    const int bb = m0 >> 11;
    const int nbase = m0 & 2047;
    const int hglob0 = (bn & 3)*256 + wc*64;
    #pragma unroll
    for (int rr = 0; rr < 2; ++rr){
      const int R = 2*wr + rr;
      asm volatile("" ::: "memory");
      #pragma unroll
      for (int ni=0;ni<4;ni++){
        int col0 = hglob0 + ni*16 + g*4;
        float4 bv4 = *(const float4*)&bias[col0];
        #pragma unroll
        for (int mi2=0;mi2<4;mi2++){
          short4 pk;
          pk.x = f2bf(acc[rr*4+mi2][ni][0] + bv4.x);
          pk.y = f2bf(acc[rr*4+mi2][ni][1] + bv4.y);
          pk.z = f2bf(acc[rr*4+mi2][ni][2] + bv4.z);
          pk.w = f2bf(acc[rr*4+mi2][ni][3] + bv4.w);
          *(short4*)&S[(mi2*16 + c)*68 + ni*16 + g*4] = pk;
        }
      }
      asm volatile("" ::: "memory");
      #pragma unroll
      for (int k=0;k<8;++k){
        int hr = (l>>3) + k*8;
        int ng = l & 7;
        s16x8 sv;
        #pragma unroll
        for (int e=0;e<8;e++) sv[e] = S[(ng*8+e)*68 + hr];
        *(s16x8*)&Vt[((size_t)bb*HH + hglob0 + hr)*NN + nbase + R*64 + ng*8] = sv;
      }
    }
  }
}

// ---------------- kernel 2: P = exp2(Q K^T * scale*log2e), 128x256 strips ------
// 512 threads = 8 waves (2q x 4k). Single-buffer 24 KiB, 2-barrier structure
// (high occupancy; cross-block overlap hides latency — m114). Strips packed at
// cum(tr) = (tr+1)^2/4; masked cols store P=0. 576 blocks, uniform 32 steps.
__global__ __launch_bounds__(512) void k_s(const short* __restrict__ Qw,
                                           const short* __restrict__ Kw,
                                           short* __restrict__ Pp){
  __shared__ short Ql[128*32];
  __shared__ short Kl[256*32];
  const int t = threadIdx.x, l = t & 63, w = t >> 6;
  const int g = l >> 4, c = l & 15;
  int p = blockIdx.x; int b = p & 7; int si = p >> 3;       // strip 0..71
  int tr = 0; while ((((tr+2)*(tr+2)) >> 2) <= si) tr++;
  int tcp = si - (((tr+1)*(tr+1)) >> 2);
  const float SC_EXP = 0.04508422002783268f;   // (1/32) * log2(e)
  const int wq = w >> 2, wk = w & 3;
  f32x4 acc[4][4] = {};

  const int sr = t >> 2, sch = t & 3;
  const int su  = sch ^ ((sr >> 1) & 3);
  const int su2 = sch ^ (((sr + 128) >> 1) & 3);
  const short* Qs  = Qw + ((size_t)(b*NN + tr*128  + sr))*HH + su*8;
  const short* Ks0 = Kw + ((size_t)(b*NN + tcp*256 + sr))*HH + su*8;
  const short* Ks1 = Kw + ((size_t)(b*NN + tcp*256 + sr + 128))*HH + su2*8;

  const int rchunk = (g ^ ((c>>1)&3)) * 8;
  int qoff[4], koff[4];
  #pragma unroll
  for (int mi=0;mi<4;mi++) qoff[mi] = (wq*64 + mi*16 + c)*32 + rchunk;
  #pragma unroll
  for (int ni=0;ni<4;ni++) koff[ni] = (wk*64 + ni*16 + c)*32 + rchunk;

  for (int kt = 0; kt < 32; ++kt){
    int ko = kt*32;
    __syncthreads();
    GL16(Qs  + ko, (char*)Ql + t*16);
    GL16(Ks0 + ko, (char*)Kl + t*16);
    GL16(Ks1 + ko, (char*)Kl + 8192 + t*16);
    __syncthreads();
    s16x8 qf[4], kf[4];
    #pragma unroll
    for (int ni=0;ni<4;ni++) kf[ni] = *(const s16x8*)&Kl[koff[ni]];
    #pragma unroll
    for (int mi=0;mi<4;mi++) qf[mi] = *(const s16x8*)&Ql[qoff[mi]];
    #pragma unroll
    for (int mi=0;mi<4;mi++)
      #pragma unroll
      for (int ni=0;ni<4;ni++)
        acc[mi][ni] = MFMA(kf[ni], qf[mi], acc[mi][ni]);
  }

  short* Pt = Pp + ((size_t)(b*72 + si))*32768;    // strip: [128][256] bf16
  #pragma unroll
  for (int ni=0;ni<4;ni++){
    int pc0 = wk*64 + ni*16 + g*4;
    #pragma unroll
    for (int mi=0;mi<4;mi++){
      int pr = wq*64 + mi*16 + c;
      short4 pk;
      #pragma unroll
      for (int i=0;i<4;i++){
        bool keep = (tcp*256 + pc0 + i) <= (tr*128 + pr);
        float pv = keep ? exp2f(acc[mi][ni][i]*SC_EXP) : 0.f;
        ((short*)&pk)[i] = f2bf(pv);
      }
      *(short4*)&Pt[pr*256 + pc0] = pk;
    }
  }
}

// ---------------- kernel 3: O = (P V) / rowsum(P), 128x256 output tiles --------
// 512 threads = 8 waves (2q x 4h). 512 blocks, 2 rounds pairing tr with 15-tr
// -> every CU's two resident blocks total exactly 72 steps. Single-buffer
// 24 KiB, 2-barrier structure. float4 stores.
__global__ __launch_bounds__(512) void k_pv(const short* __restrict__ Pp,
                                            const short* __restrict__ Vt,
                                            float* __restrict__ out){
  __shared__ short Pl[128*32];
  __shared__ short Vl[256*32];
  const int t = threadIdx.x, l = t & 63, w = t >> 6;
  const int g = l >> 4, c = l & 15;
  int p = blockIdx.x;
  int r = p >> 8, j = p & 255;
  int tr = r ? (15 - (j >> 4)) : (j >> 4);
  int id = r ? (16 + (j & 15)) : (j & 15);     // 32 ids: b(3b) | hc(2b)
  int b = id & 7, hc = id >> 3;                // hc 0..3
  const short* Pb = Pp + ((size_t)(b*72 + (((tr+1)*(tr+1))>>2)))*32768;
  const int wq = w >> 2, wh = w & 3;
  f32x4 acc[4][4] = {};
  float ls[4] = {0.f,0.f,0.f,0.f};

  const int sr = t >> 2, sch = t & 3;
  const int su  = sch ^ ((sr >> 1) & 3);
  const int su2 = sch ^ (((sr + 128) >> 1) & 3);
  const short* Vs0 = Vt + ((size_t)(b*HH + hc*256 + sr))*NN + su*8;
  const short* Vs1 = Vt + ((size_t)(b*HH + hc*256 + sr + 128))*NN + su2*8;

  const int rchunk = (g ^ ((c>>1)&3)) * 8;
  int poff[4], voff[4];
  #pragma unroll
  for (int mi=0;mi<4;mi++) poff[mi] = (wq*64 + mi*16 + c)*32 + rchunk;
  #pragma unroll
  for (int ni=0;ni<4;ni++) voff[ni] = (wh*64 + ni*16 + c)*32 + rchunk;

  const int nst = ((tr + 2) >> 1) * 8;         // strips * 8 steps
  for (int kt = 0; kt < nst; ++kt){
    const short* Ps = Pb + (size_t)(kt>>3)*32768 + (kt&7)*32;
    __syncthreads();
    GL16(Ps + sr*256 + su*8, (char*)Pl + t*16);
    GL16(Vs0 + kt*32, (char*)Vl + t*16);
    GL16(Vs1 + kt*32, (char*)Vl + 8192 + t*16);
    __syncthreads();
    s16x8 pf[4], vf[4];
    #pragma unroll
    for (int ni=0;ni<4;ni++) vf[ni] = *(const s16x8*)&Vl[voff[ni]];
    #pragma unroll
    for (int mi=0;mi<4;mi++) pf[mi] = *(const s16x8*)&Pl[poff[mi]];
    #pragma unroll
    for (int mi=0;mi<4;mi++){
      #pragma unroll
      for (int e=0;e<8;e++) ls[mi] += bf2f(pf[mi][e]);   // row-sum of P
    }
    #pragma unroll
    for (int mi=0;mi<4;mi++)
      #pragma unroll
      for (int ni=0;ni<4;ni++)
        acc[mi][ni] = MFMA(vf[ni], pf[mi], acc[mi][ni]);
  }
  #pragma unroll
  for (int mi=0;mi<4;mi++){
    ls[mi] += __shfl_xor(ls[mi], 16);
    ls[mi] += __shfl_xor(ls[mi], 32);    // full row-sum; lane row = wq*64+mi*16+c
  }
  #pragma unroll
  for (int mi=0;mi<4;mi++){
    float linv = 1.0f / ls[mi];
    int orow = tr*128 + wq*64 + mi*16 + c;
    #pragma unroll
    for (int ni=0;ni<4;ni++){
      int h0 = hc*256 + wh*64 + ni*16 + g*4;
      float4 o4;
      o4.x = acc[mi][ni][0]*linv; o4.y = acc[mi][ni][1]*linv;
      o4.z = acc[mi][ni][2]*linv; o4.w = acc[mi][ni][3]*linv;
      *(float4*)&out[((size_t)(b*NN + orow))*HH + h0] = o4;
    }
  }
}

extern "C" void kernel_launch(void* const* d_in, const int* in_sizes, int n_in,
                              void* d_out, int out_size, void* d_ws, size_t ws_size,
                              hipStream_t stream) {
  const float* x  = (const float*)d_in[0];
  const float* Wq = (const float*)d_in[1];
  const float* bq = (const float*)d_in[2];
  const float* Wk = (const float*)d_in[3];
  const float* bk = (const float*)d_in[4];
  const float* Wv = (const float*)d_in[5];
  const float* bv = (const float*)d_in[6];
  char* ws = (char*)d_ws;
  // ws layout (bytes). Pp (37.75 MB) OVERLAYS xb+Wt (both dead after k_gemm,
  // and k_s writes Pp only afterwards).
  short* xb = (short*)(ws);                         // 33,554,432
  short* Pp = (short*)(ws);                         // 37,748,736 (overlay)
  short* Wt = (short*)(ws + 33554432u);             //  6,291,456
  short* Qw = (short*)(ws + 41943040u);             // 33,554,432
  short* Kw = (short*)(ws + 75497472u);             // 33,554,432
  short* Vt = (short*)(ws + 109051904u);            // 33,554,432

  k_conv_x<<<8192, 256, 0, stream>>>(x, xb);
  k_conv_w<<<768, 256, 0, stream>>>(Wq, Wk, Wv, Wt);
  k_gemm<<<768, 512, 0, stream>>>(xb, Wt, bq, bk, bv, Qw, Kw, Vt);
  k_s<<<576, 512, 0, stream>>>(Qw, Kw, Pp);
  k_pv<<<512, 512, 0, stream>>>(Pp, Vt, (float*)d_out);
}

// Round 17
// 280.459 us; speedup vs baseline: 1.1792x; 1.0008x over previous
//
#include <hip/hip_runtime.h>
#include <hip/hip_bf16.h>
#include <stdint.h>

#define BB 8
#define NN 2048
#define DD 1024
#define HH 1024

using f32x4 = __attribute__((ext_vector_type(4))) float;
using s16x8 = __attribute__((ext_vector_type(8))) short;

__device__ __forceinline__ short f2bf(float f){
  union { float f; uint32_t u; } v; v.f = f;
  uint32_t r = (v.u + 0x7fffu + ((v.u >> 16) & 1u)) >> 16;
  return (short)r;
}
__device__ __forceinline__ float bf2f(short s){
  union { uint32_t u; float f; } v; v.u = ((uint32_t)(uint16_t)s) << 16; return v.f;
}

#define MFMA(a,b,c) __builtin_amdgcn_mfma_f32_16x16x32_bf16((a),(b),(c),0,0,0)

// async global->LDS, 16B per lane. LDS dest is wave-uniform base + lane*16.
#define GL16(gp, lp) __builtin_amdgcn_global_load_lds( \
    (const __attribute__((address_space(1))) void*)(gp), \
    (__attribute__((address_space(3))) void*)(lp), 16, 0, 0)

// ---------------- kernel 0a: x fp32 -> bf16 ----------------
__global__ __launch_bounds__(256) void k_conv_x(const float* __restrict__ x,
                                                short* __restrict__ xb){
  int gid = blockIdx.x*256 + threadIdx.x;
  const float4* xv = (const float4*)x;
  float4 a = xv[(size_t)gid*2], b2 = xv[(size_t)gid*2+1];
  s16x8 o;
  o[0]=f2bf(a.x);  o[1]=f2bf(a.y);  o[2]=f2bf(a.z);  o[3]=f2bf(a.w);
  o[4]=f2bf(b2.x); o[5]=f2bf(b2.y); o[6]=f2bf(b2.z); o[7]=f2bf(b2.w);
  *(s16x8*)(xb + (size_t)gid*8) = o;
}

// ---------------- kernel 0b: pack W^T bf16 [3072][1024] ----------------
__global__ __launch_bounds__(256) void k_conv_w(const float* __restrict__ Wq,
                                                const float* __restrict__ Wk,
                                                const float* __restrict__ Wv,
                                                short* __restrict__ Wt){
  __shared__ float tile[64][65];
  int bx = blockIdx.x; int mat = bx >> 8; int ti = bx & 255;
  int d0 = (ti >> 4) << 6, h0 = (ti & 15) << 6;
  const float* W = (mat==0) ? Wq : (mat==1 ? Wk : Wv);
  int t = threadIdx.x;
  for (int i=0;i<16;i++){ int e = i*256 + t; int r = e>>6, c = e&63;
    tile[r][c] = W[(size_t)(d0+r)*HH + h0 + c]; }
  __syncthreads();
  for (int i=0;i<16;i++){ int e = i*256 + t; int r = e>>6, c = e&63;
    Wt[(size_t)(mat*HH + h0 + r)*DD + d0 + c] = f2bf(tile[c][r]); }
}

// ---------------- kernel 1: QKV GEMM, rolling 4-slot BK=32 pipeline ------------
// R12/R14-proven form (903 TF — the non-fine-interleave structural ceiling,
// confirmed across 6 structural variants R5-R15).
// V-blocks (bn>=8) write Vt[b][h][n] directly via per-wave LDS transpose.
__global__ __launch_bounds__(512,2) void k_gemm(const short* __restrict__ Aw,
                                                const short* __restrict__ Bw,
                                                const float* __restrict__ bq,
                                                const float* __restrict__ bk,
                                                const float* __restrict__ bv,
                                                short* __restrict__ Qw,
                                                short* __restrict__ Kw,
                                                short* __restrict__ Vt){
  __shared__ short Al[4][256*32];
  __shared__ short Bl[4][256*32];
  const int t = threadIdx.x, l = t & 63, w = t >> 6;
  const int g = l >> 4, c = l & 15;
  const int bid = blockIdx.x;
  const int bm = (bid & 7)*8 + ((bid >> 3) & 7);   // 0..63
  const int bn = bid >> 6;                          // 0..11
  const int m0 = bm << 8, c0 = bn << 8;
  const int wr = w >> 2, wc = w & 3;
  f32x4 acc[8][4] = {};

  const int sr = t >> 2, sch = t & 3;
  const int u0 = sch ^ ((sr >> 1) & 3);
  const int u1 = sch ^ (((sr + 128) >> 1) & 3);
  const short* A0 = Aw + (size_t)(m0 + sr)*DD + u0*8;
  const short* A1 = Aw + (size_t)(m0 + sr + 128)*DD + u1*8;
  const short* B0 = Bw + (size_t)(c0 + sr)*DD + u0*8;
  const short* B1 = Bw + (size_t)(c0 + sr + 128)*DD + u1*8;
  const int d0b = sr*64 + sch*16, d1b = (sr+128)*64 + sch*16;
  auto stage = [&](int kt){
    int s = kt & 3, ko = kt*32;
    GL16(A0 + ko, (char*)&Al[s][0] + d0b);
    GL16(A1 + ko, (char*)&Al[s][0] + d1b);
    GL16(B0 + ko, (char*)&Bl[s][0] + d0b);
    GL16(B1 + ko, (char*)&Bl[s][0] + d1b);
  };

  int aoff[8], boff[4];
  #pragma unroll
  for (int mi=0;mi<8;mi++){
    int row = wr*128 + mi*16 + c;
    aoff[mi] = row*32 + (g ^ ((row>>1)&3))*8;
  }
  #pragma unroll
  for (int ni=0;ni<4;ni++){
    int row = wc*64 + ni*16 + c;
    boff[ni] = row*32 + (g ^ ((row>>1)&3))*8;
  }

  auto body = [&](int kt, bool dostage){
    int s = kt & 3;
    __builtin_amdgcn_sched_barrier(0);
    __builtin_amdgcn_s_barrier();
    __builtin_amdgcn_sched_barrier(0);
    s16x8 bfr[4], af[8];
    #pragma unroll
    for (int ni=0;ni<4;ni++) bfr[ni] = *(const s16x8*)&Bl[s][boff[ni]];
    #pragma unroll
    for (int mi=0;mi<8;mi++) af[mi] = *(const s16x8*)&Al[s][aoff[mi]];
    if (dostage) stage(kt+3);
    __builtin_amdgcn_s_setprio(1);
    #pragma unroll
    for (int mi=0;mi<8;mi++)
      #pragma unroll
      for (int ni=0;ni<4;ni++)
        acc[mi][ni] = MFMA(bfr[ni], af[mi], acc[mi][ni]);
    __builtin_amdgcn_s_setprio(0);
  };

  stage(0); stage(1); stage(2);
  for (int kt = 0; kt < 30; ++kt){
    asm volatile("s_waitcnt vmcnt(8)" ::: "memory");
    body(kt, kt < 29);
  }
  asm volatile("s_waitcnt vmcnt(4)" ::: "memory");
  body(30, false);
  asm volatile("s_waitcnt vmcnt(0)" ::: "memory");
  body(31, false);

  const int mat = bn >> 2;
  const float* bias = (mat==0) ? bq : (mat==1 ? bk : bv);
  if (mat < 2){
    short* Outp = (mat==0) ? Qw : Kw;
    #pragma unroll
    for (int ni=0;ni<4;ni++){
      int col0 = (bn & 3)*256 + wc*64 + ni*16 + g*4;
      float4 bv4 = *(const float4*)&bias[col0];
      #pragma unroll
      for (int mi=0;mi<8;mi++){
        int orow = m0 + wr*128 + mi*16 + c;
        short4 pk;
        pk.x = f2bf(acc[mi][ni][0] + bv4.x);
        pk.y = f2bf(acc[mi][ni][1] + bv4.y);
        pk.z = f2bf(acc[mi][ni][2] + bv4.z);
        pk.w = f2bf(acc[mi][ni][3] + bv4.w);
        *(short4*)&Outp[(size_t)orow*HH + col0] = pk;
      }
    }
  } else {
    // V: per-wave LDS transpose into Vt[b][h][n].
    short* S = (w < 4) ? ((short*)&Al[0][0] + w*4352)
                       : ((short*)&Bl[0][0] + (w-4)*4352);
    const int bb = m0 >> 11;
    const int nbase = m0 & 2047;
    const int hglob0 = (bn & 3)*256 + wc*64;
    #pragma unroll
    for (int rr = 0; rr < 2; ++rr){
      const int R = 2*wr + rr;
      asm volatile("" ::: "memory");
      #pragma unroll
      for (int ni=0;ni<4;ni++){
        int col0 = hglob0 + ni*16 + g*4;
        float4 bv4 = *(const float4*)&bias[col0];
        #pragma unroll
        for (int mi2=0;mi2<4;mi2++){
          short4 pk;
          pk.x = f2bf(acc[rr*4+mi2][ni][0] + bv4.x);
          pk.y = f2bf(acc[rr*4+mi2][ni][1] + bv4.y);
          pk.z = f2bf(acc[rr*4+mi2][ni][2] + bv4.z);
          pk.w = f2bf(acc[rr*4+mi2][ni][3] + bv4.w);
          *(short4*)&S[(mi2*16 + c)*68 + ni*16 + g*4] = pk;
        }
      }
      asm volatile("" ::: "memory");
      #pragma unroll
      for (int k=0;k<8;++k){
        int hr = (l>>3) + k*8;
        int ng = l & 7;
        s16x8 sv;
        #pragma unroll
        for (int e=0;e<8;e++) sv[e] = S[(ng*8+e)*68 + hr];
        *(s16x8*)&Vt[((size_t)bb*HH + hglob0 + hr)*NN + nbase + R*64 + ng*8] = sv;
      }
    }
  }
}

// ---------------- kernel 2: P = exp2(Q K^T * scale*log2e), 128x256 strips ------
// 512 threads = 8 waves (2q x 4k). Single-buffer 24 KiB, 2-barrier structure
// (high occupancy; cross-block overlap hides latency — m114). Strips packed at
// cum(tr) = (tr+1)^2/4; masked cols store P=0. 576 blocks, uniform 32 steps.
__global__ __launch_bounds__(512) void k_s(const short* __restrict__ Qw,
                                           const short* __restrict__ Kw,
                                           short* __restrict__ Pp){
  __shared__ short Ql[128*32];
  __shared__ short Kl[256*32];
  const int t = threadIdx.x, l = t & 63, w = t >> 6;
  const int g = l >> 4, c = l & 15;
  int p = blockIdx.x; int b = p & 7; int si = p >> 3;       // strip 0..71
  int tr = 0; while ((((tr+2)*(tr+2)) >> 2) <= si) tr++;
  int tcp = si - (((tr+1)*(tr+1)) >> 2);
  const float SC_EXP = 0.04508422002783268f;   // (1/32) * log2(e)
  const int wq = w >> 2, wk = w & 3;
  f32x4 acc[4][4] = {};

  const int sr = t >> 2, sch = t & 3;
  const int su  = sch ^ ((sr >> 1) & 3);
  const int su2 = sch ^ (((sr + 128) >> 1) & 3);
  const short* Qs  = Qw + ((size_t)(b*NN + tr*128  + sr))*HH + su*8;
  const short* Ks0 = Kw + ((size_t)(b*NN + tcp*256 + sr))*HH + su*8;
  const short* Ks1 = Kw + ((size_t)(b*NN + tcp*256 + sr + 128))*HH + su2*8;

  const int rchunk = (g ^ ((c>>1)&3)) * 8;
  int qoff[4], koff[4];
  #pragma unroll
  for (int mi=0;mi<4;mi++) qoff[mi] = (wq*64 + mi*16 + c)*32 + rchunk;
  #pragma unroll
  for (int ni=0;ni<4;ni++) koff[ni] = (wk*64 + ni*16 + c)*32 + rchunk;

  for (int kt = 0; kt < 32; ++kt){
    int ko = kt*32;
    __syncthreads();
    GL16(Qs  + ko, (char*)Ql + t*16);
    GL16(Ks0 + ko, (char*)Kl + t*16);
    GL16(Ks1 + ko, (char*)Kl + 8192 + t*16);
    __syncthreads();
    s16x8 qf[4], kf[4];
    #pragma unroll
    for (int ni=0;ni<4;ni++) kf[ni] = *(const s16x8*)&Kl[koff[ni]];
    #pragma unroll
    for (int mi=0;mi<4;mi++) qf[mi] = *(const s16x8*)&Ql[qoff[mi]];
    #pragma unroll
    for (int mi=0;mi<4;mi++)
      #pragma unroll
      for (int ni=0;ni<4;ni++)
        acc[mi][ni] = MFMA(kf[ni], qf[mi], acc[mi][ni]);
  }

  short* Pt = Pp + ((size_t)(b*72 + si))*32768;    // strip: [128][256] bf16
  #pragma unroll
  for (int ni=0;ni<4;ni++){
    int pc0 = wk*64 + ni*16 + g*4;
    #pragma unroll
    for (int mi=0;mi<4;mi++){
      int pr = wq*64 + mi*16 + c;
      short4 pk;
      #pragma unroll
      for (int i=0;i<4;i++){
        bool keep = (tcp*256 + pc0 + i) <= (tr*128 + pr);
        float pv = keep ? exp2f(acc[mi][ni][i]*SC_EXP) : 0.f;
        ((short*)&pk)[i] = f2bf(pv);
      }
      *(short4*)&Pt[pr*256 + pc0] = pk;
    }
  }
}

// ---------------- kernel 3: O = (P V) / rowsum(P), 128x256 output tiles --------
// 512 threads = 8 waves (2q x 4h). 512 blocks, 2 rounds pairing tr with 15-tr.
// nst TRIMMED to exactly the causal extent: (tr+1)*4 steps (= (tr+1)*128 keys)
// — the padded zero half-strip for even tr contributed 0 to acc AND ls, so
// skipping it is bit-exact. Pairing stays constant: 4(tr+1)+4(16-tr) = 68
// steps per CU pair (was 72). Single-buffer 24 KiB, 2-barrier structure.
__global__ __launch_bounds__(512) void k_pv(const short* __restrict__ Pp,
                                            const short* __restrict__ Vt,
                                            float* __restrict__ out){
  __shared__ short Pl[128*32];
  __shared__ short Vl[256*32];
  const int t = threadIdx.x, l = t & 63, w = t >> 6;
  const int g = l >> 4, c = l & 15;
  int p = blockIdx.x;
  int r = p >> 8, j = p & 255;
  int tr = r ? (15 - (j >> 4)) : (j >> 4);
  int id = r ? (16 + (j & 15)) : (j & 15);     // 32 ids: b(3b) | hc(2b)
  int b = id & 7, hc = id >> 3;                // hc 0..3
  const short* Pb = Pp + ((size_t)(b*72 + (((tr+1)*(tr+1))>>2)))*32768;
  const int wq = w >> 2, wh = w & 3;
  f32x4 acc[4][4] = {};
  float ls[4] = {0.f,0.f,0.f,0.f};

  const int sr = t >> 2, sch = t & 3;
  const int su  = sch ^ ((sr >> 1) & 3);
  const int su2 = sch ^ (((sr + 128) >> 1) & 3);
  const short* Vs0 = Vt + ((size_t)(b*HH + hc*256 + sr))*NN + su*8;
  const short* Vs1 = Vt + ((size_t)(b*HH + hc*256 + sr + 128))*NN + su2*8;

  const int rchunk = (g ^ ((c>>1)&3)) * 8;
  int poff[4], voff[4];
  #pragma unroll
  for (int mi=0;mi<4;mi++) poff[mi] = (wq*64 + mi*16 + c)*32 + rchunk;
  #pragma unroll
  for (int ni=0;ni<4;ni++) voff[ni] = (wh*64 + ni*16 + c)*32 + rchunk;

  const int nst = (tr + 1) * 4;                // exact causal extent (trimmed)
  for (int kt = 0; kt < nst; ++kt){
    const short* Ps = Pb + (size_t)(kt>>3)*32768 + (kt&7)*32;
    __syncthreads();
    GL16(Ps + sr*256 + su*8, (char*)Pl + t*16);
    GL16(Vs0 + kt*32, (char*)Vl + t*16);
    GL16(Vs1 + kt*32, (char*)Vl + 8192 + t*16);
    __syncthreads();
    s16x8 pf[4], vf[4];
    #pragma unroll
    for (int ni=0;ni<4;ni++) vf[ni] = *(const s16x8*)&Vl[voff[ni]];
    #pragma unroll
    for (int mi=0;mi<4;mi++) pf[mi] = *(const s16x8*)&Pl[poff[mi]];
    #pragma unroll
    for (int mi=0;mi<4;mi++){
      #pragma unroll
      for (int e=0;e<8;e++) ls[mi] += bf2f(pf[mi][e]);   // row-sum of P
    }
    #pragma unroll
    for (int mi=0;mi<4;mi++)
      #pragma unroll
      for (int ni=0;ni<4;ni++)
        acc[mi][ni] = MFMA(vf[ni], pf[mi], acc[mi][ni]);
  }
  #pragma unroll
  for (int mi=0;mi<4;mi++){
    ls[mi] += __shfl_xor(ls[mi], 16);
    ls[mi] += __shfl_xor(ls[mi], 32);    // full row-sum; lane row = wq*64+mi*16+c
  }
  #pragma unroll
  for (int mi=0;mi<4;mi++){
    float linv = 1.0f / ls[mi];
    int orow = tr*128 + wq*64 + mi*16 + c;
    #pragma unroll
    for (int ni=0;ni<4;ni++){
      int h0 = hc*256 + wh*64 + ni*16 + g*4;
      float4 o4;
      o4.x = acc[mi][ni][0]*linv; o4.y = acc[mi][ni][1]*linv;
      o4.z = acc[mi][ni][2]*linv; o4.w = acc[mi][ni][3]*linv;
      *(float4*)&out[((size_t)(b*NN + orow))*HH + h0] = o4;
    }
  }
}

extern "C" void kernel_launch(void* const* d_in, const int* in_sizes, int n_in,
                              void* d_out, int out_size, void* d_ws, size_t ws_size,
                              hipStream_t stream) {
  const float* x  = (const float*)d_in[0];
  const float* Wq = (const float*)d_in[1];
  const float* bq = (const float*)d_in[2];
  const float* Wk = (const float*)d_in[3];
  const float* bk = (const float*)d_in[4];
  const float* Wv = (const float*)d_in[5];
  const float* bv = (const float*)d_in[6];
  char* ws = (char*)d_ws;
  // ws layout (bytes). Pp (37.75 MB) OVERLAYS xb+Wt (both dead after k_gemm,
  // and k_s writes Pp only afterwards).
  short* xb = (short*)(ws);                         // 33,554,432
  short* Pp = (short*)(ws);                         // 37,748,736 (overlay)
  short* Wt = (short*)(ws + 33554432u);             //  6,291,456
  short* Qw = (short*)(ws + 41943040u);             // 33,554,432
  short* Kw = (short*)(ws + 75497472u);             // 33,554,432
  short* Vt = (short*)(ws + 109051904u);            // 33,554,432

  k_conv_x<<<8192, 256, 0, stream>>>(x, xb);
  k_conv_w<<<768, 256, 0, stream>>>(Wq, Wk, Wv, Wt);
  k_gemm<<<768, 512, 0, stream>>>(xb, Wt, bq, bk, bv, Qw, Kw, Vt);
  k_s<<<576, 512, 0, stream>>>(Qw, Kw, Pp);
  k_pv<<<512, 512, 0, stream>>>(Pp, Vt, (float*)d_out);
}

// Round 18
// 252.797 us; speedup vs baseline: 1.3082x; 1.1094x over previous
//
#include <hip/hip_runtime.h>
#include <hip/hip_bf16.h>
#include <stdint.h>

#define BB 8
#define NN 2048
#define DD 1024
#define HH 1024

using f32x4 = __attribute__((ext_vector_type(4))) float;
using s16x8 = __attribute__((ext_vector_type(8))) short;

__device__ __forceinline__ short f2bf(float f){
  union { float f; uint32_t u; } v; v.f = f;
  uint32_t r = (v.u + 0x7fffu + ((v.u >> 16) & 1u)) >> 16;
  return (short)r;
}
__device__ __forceinline__ float bf2f(short s){
  union { uint32_t u; float f; } v; v.u = ((uint32_t)(uint16_t)s) << 16; return v.f;
}

#define MFMA(a,b,c) __builtin_amdgcn_mfma_f32_16x16x32_bf16((a),(b),(c),0,0,0)

// async global->LDS, 16B per lane. LDS dest is wave-uniform base + lane*16.
#define GL16(gp, lp) __builtin_amdgcn_global_load_lds( \
    (const __attribute__((address_space(1))) void*)(gp), \
    (__attribute__((address_space(3))) void*)(lp), 16, 0, 0)

// ---------------- kernel 0a: x fp32 -> bf16 ----------------
__global__ __launch_bounds__(256) void k_conv_x(const float* __restrict__ x,
                                                short* __restrict__ xb){
  int gid = blockIdx.x*256 + threadIdx.x;
  const float4* xv = (const float4*)x;
  float4 a = xv[(size_t)gid*2], b2 = xv[(size_t)gid*2+1];
  s16x8 o;
  o[0]=f2bf(a.x);  o[1]=f2bf(a.y);  o[2]=f2bf(a.z);  o[3]=f2bf(a.w);
  o[4]=f2bf(b2.x); o[5]=f2bf(b2.y); o[6]=f2bf(b2.z); o[7]=f2bf(b2.w);
  *(s16x8*)(xb + (size_t)gid*8) = o;
}

// ---------------- kernel 0b: pack W^T bf16 [3072][1024] ----------------
__global__ __launch_bounds__(256) void k_conv_w(const float* __restrict__ Wq,
                                                const float* __restrict__ Wk,
                                                const float* __restrict__ Wv,
                                                short* __restrict__ Wt){
  __shared__ float tile[64][65];
  int bx = blockIdx.x; int mat = bx >> 8; int ti = bx & 255;
  int d0 = (ti >> 4) << 6, h0 = (ti & 15) << 6;
  const float* W = (mat==0) ? Wq : (mat==1 ? Wk : Wv);
  int t = threadIdx.x;
  for (int i=0;i<16;i++){ int e = i*256 + t; int r = e>>6, c = e&63;
    tile[r][c] = W[(size_t)(d0+r)*HH + h0 + c]; }
  __syncthreads();
  for (int i=0;i<16;i++){ int e = i*256 + t; int r = e>>6, c = e&63;
    Wt[(size_t)(mat*HH + h0 + r)*DD + d0 + c] = f2bf(tile[c][r]); }
}

// ---------------- kernel 1: QKV GEMM, rolling 4-slot BK=32 pipeline ------------
// R12/R14-proven form (903 TF). V-blocks (bn>=8) write Vt[b][h][n] directly.
__global__ __launch_bounds__(512,2) void k_gemm(const short* __restrict__ Aw,
                                                const short* __restrict__ Bw,
                                                const float* __restrict__ bq,
                                                const float* __restrict__ bk,
                                                const float* __restrict__ bv,
                                                short* __restrict__ Qw,
                                                short* __restrict__ Kw,
                                                short* __restrict__ Vt){
  __shared__ short Al[4][256*32];
  __shared__ short Bl[4][256*32];
  const int t = threadIdx.x, l = t & 63, w = t >> 6;
  const int g = l >> 4, c = l & 15;
  const int bid = blockIdx.x;
  const int bm = (bid & 7)*8 + ((bid >> 3) & 7);   // 0..63
  const int bn = bid >> 6;                          // 0..11
  const int m0 = bm << 8, c0 = bn << 8;
  const int wr = w >> 2, wc = w & 3;
  f32x4 acc[8][4] = {};

  const int sr = t >> 2, sch = t & 3;
  const int u0 = sch ^ ((sr >> 1) & 3);
  const int u1 = sch ^ (((sr + 128) >> 1) & 3);
  const short* A0 = Aw + (size_t)(m0 + sr)*DD + u0*8;
  const short* A1 = Aw + (size_t)(m0 + sr + 128)*DD + u1*8;
  const short* B0 = Bw + (size_t)(c0 + sr)*DD + u0*8;
  const short* B1 = Bw + (size_t)(c0 + sr + 128)*DD + u1*8;
  const int d0b = sr*64 + sch*16, d1b = (sr+128)*64 + sch*16;
  auto stage = [&](int kt){
    int s = kt & 3, ko = kt*32;
    GL16(A0 + ko, (char*)&Al[s][0] + d0b);
    GL16(A1 + ko, (char*)&Al[s][0] + d1b);
    GL16(B0 + ko, (char*)&Bl[s][0] + d0b);
    GL16(B1 + ko, (char*)&Bl[s][0] + d1b);
  };

  int aoff[8], boff[4];
  #pragma unroll
  for (int mi=0;mi<8;mi++){
    int row = wr*128 + mi*16 + c;
    aoff[mi] = row*32 + (g ^ ((row>>1)&3))*8;
  }
  #pragma unroll
  for (int ni=0;ni<4;ni++){
    int row = wc*64 + ni*16 + c;
    boff[ni] = row*32 + (g ^ ((row>>1)&3))*8;
  }

  auto body = [&](int kt, bool dostage){
    int s = kt & 3;
    __builtin_amdgcn_sched_barrier(0);
    __builtin_amdgcn_s_barrier();
    __builtin_amdgcn_sched_barrier(0);
    s16x8 bfr[4], af[8];
    #pragma unroll
    for (int ni=0;ni<4;ni++) bfr[ni] = *(const s16x8*)&Bl[s][boff[ni]];
    #pragma unroll
    for (int mi=0;mi<8;mi++) af[mi] = *(const s16x8*)&Al[s][aoff[mi]];
    if (dostage) stage(kt+3);
    __builtin_amdgcn_s_setprio(1);
    #pragma unroll
    for (int mi=0;mi<8;mi++)
      #pragma unroll
      for (int ni=0;ni<4;ni++)
        acc[mi][ni] = MFMA(bfr[ni], af[mi], acc[mi][ni]);
    __builtin_amdgcn_s_setprio(0);
  };

  stage(0); stage(1); stage(2);
  for (int kt = 0; kt < 30; ++kt){
    asm volatile("s_waitcnt vmcnt(8)" ::: "memory");
    body(kt, kt < 29);
  }
  asm volatile("s_waitcnt vmcnt(4)" ::: "memory");
  body(30, false);
  asm volatile("s_waitcnt vmcnt(0)" ::: "memory");
  body(31, false);

  const int mat = bn >> 2;
  const float* bias = (mat==0) ? bq : (mat==1 ? bk : bv);
  if (mat < 2){
    short* Outp = (mat==0) ? Qw : Kw;
    #pragma unroll
    for (int ni=0;ni<4;ni++){
      int col0 = (bn & 3)*256 + wc*64 + ni*16 + g*4;
      float4 bv4 = *(const float4*)&bias[col0];
      #pragma unroll
      for (int mi=0;mi<8;mi++){
        int orow = m0 + wr*128 + mi*16 + c;
        short4 pk;
        pk.x = f2bf(acc[mi][ni][0] + bv4.x);
        pk.y = f2bf(acc[mi][ni][1] + bv4.y);
        pk.z = f2bf(acc[mi][ni][2] + bv4.z);
        pk.w = f2bf(acc[mi][ni][3] + bv4.w);
        *(short4*)&Outp[(size_t)orow*HH + col0] = pk;
      }
    }
  } else {
    // V: per-wave LDS transpose into Vt[b][h][n].
    short* S = (w < 4) ? ((short*)&Al[0][0] + w*4352)
                       : ((short*)&Bl[0][0] + (w-4)*4352);
    const int bb = m0 >> 11;
    const int nbase = m0 & 2047;
    const int hglob0 = (bn & 3)*256 + wc*64;
    #pragma unroll
    for (int rr = 0; rr < 2; ++rr){
      const int R = 2*wr + rr;
      asm volatile("" ::: "memory");
      #pragma unroll
      for (int ni=0;ni<4;ni++){
        int col0 = hglob0 + ni*16 + g*4;
        float4 bv4 = *(const float4*)&bias[col0];
        #pragma unroll
        for (int mi2=0;mi2<4;mi2++){
          short4 pk;
          pk.x = f2bf(acc[rr*4+mi2][ni][0] + bv4.x);
          pk.y = f2bf(acc[rr*4+mi2][ni][1] + bv4.y);
          pk.z = f2bf(acc[rr*4+mi2][ni][2] + bv4.z);
          pk.w = f2bf(acc[rr*4+mi2][ni][3] + bv4.w);
          *(short4*)&S[(mi2*16 + c)*68 + ni*16 + g*4] = pk;
        }
      }
      asm volatile("" ::: "memory");
      #pragma unroll
      for (int k=0;k<8;++k){
        int hr = (l>>3) + k*8;
        int ng = l & 7;
        s16x8 sv;
        #pragma unroll
        for (int e=0;e<8;e++) sv[e] = S[(ng*8+e)*68 + hr];
        *(s16x8*)&Vt[((size_t)bb*HH + hglob0 + hr)*NN + nbase + R*64 + ng*8] = sv;
      }
    }
  }
}

// ---------------- kernel 2: P = exp2(Q K^T * scale*log2e), 128x256 strips ------
// ROLLING 3-SLOT port of the k_gemm-proven pipeline: 72 KiB LDS (2 blocks/CU =
// 16 waves, k_gemm's working point), ONE raw barrier/step, counted vmcnt(3)
// (one 3-load stage stays in flight; drains only at the final step), no lgkm
// drain (compiler JIT-waits per fragment), reads -> stage(kt+2) order.
// Hazard: at barrier kt every wave vmcnt-verified stage(kt) and retired its
// slot-(kt-1) ds_reads -> stage(kt+2) may overwrite slot (kt-1)%3.
__global__ __launch_bounds__(512,2) void k_s(const short* __restrict__ Qw,
                                             const short* __restrict__ Kw,
                                             short* __restrict__ Pp){
  __shared__ short Ql[3][128*32];      // 24 KB
  __shared__ short Kl[3][256*32];      // 48 KB
  const int t = threadIdx.x, l = t & 63, w = t >> 6;
  const int g = l >> 4, c = l & 15;
  int p = blockIdx.x; int b = p & 7; int si = p >> 3;       // strip 0..71
  int tr = 0; while ((((tr+2)*(tr+2)) >> 2) <= si) tr++;
  int tcp = si - (((tr+1)*(tr+1)) >> 2);
  const float SC_EXP = 0.04508422002783268f;   // (1/32) * log2(e)
  const int wq = w >> 2, wk = w & 3;
  f32x4 acc[4][4] = {};

  const int sr = t >> 2, sch = t & 3;
  const int su  = sch ^ ((sr >> 1) & 3);
  const int su2 = sch ^ (((sr + 128) >> 1) & 3);
  const short* Qs  = Qw + ((size_t)(b*NN + tr*128  + sr))*HH + su*8;
  const short* Ks0 = Kw + ((size_t)(b*NN + tcp*256 + sr))*HH + su*8;
  const short* Ks1 = Kw + ((size_t)(b*NN + tcp*256 + sr + 128))*HH + su2*8;
  auto stage = [&](int kt){
    int s = kt % 3, ko = kt*32;
    GL16(Qs  + ko, (char*)&Ql[s][0] + t*16);
    GL16(Ks0 + ko, (char*)&Kl[s][0] + t*16);
    GL16(Ks1 + ko, (char*)&Kl[s][0] + 8192 + t*16);
  };

  const int rchunk = (g ^ ((c>>1)&3)) * 8;
  int qoff[4], koff[4];
  #pragma unroll
  for (int mi=0;mi<4;mi++) qoff[mi] = (wq*64 + mi*16 + c)*32 + rchunk;
  #pragma unroll
  for (int ni=0;ni<4;ni++) koff[ni] = (wk*64 + ni*16 + c)*32 + rchunk;

  auto body = [&](int kt, bool dostage){
    int s = kt % 3;
    __builtin_amdgcn_sched_barrier(0);
    __builtin_amdgcn_s_barrier();
    __builtin_amdgcn_sched_barrier(0);
    s16x8 qf[4], kf[4];
    #pragma unroll
    for (int ni=0;ni<4;ni++) kf[ni] = *(const s16x8*)&Kl[s][koff[ni]];
    #pragma unroll
    for (int mi=0;mi<4;mi++) qf[mi] = *(const s16x8*)&Ql[s][qoff[mi]];
    if (dostage) stage(kt+2);
    __builtin_amdgcn_s_setprio(1);
    #pragma unroll
    for (int mi=0;mi<4;mi++)
      #pragma unroll
      for (int ni=0;ni<4;ni++)
        acc[mi][ni] = MFMA(kf[ni], qf[mi], acc[mi][ni]);
    __builtin_amdgcn_s_setprio(0);
  };

  stage(0); stage(1);
  for (int kt = 0; kt < 31; ++kt){
    asm volatile("s_waitcnt vmcnt(3)" ::: "memory");
    body(kt, kt < 30);
  }
  asm volatile("s_waitcnt vmcnt(0)" ::: "memory");
  body(31, false);

  short* Pt = Pp + ((size_t)(b*72 + si))*32768;    // strip: [128][256] bf16
  #pragma unroll
  for (int ni=0;ni<4;ni++){
    int pc0 = wk*64 + ni*16 + g*4;
    #pragma unroll
    for (int mi=0;mi<4;mi++){
      int pr = wq*64 + mi*16 + c;
      short4 pk;
      #pragma unroll
      for (int i=0;i<4;i++){
        bool keep = (tcp*256 + pc0 + i) <= (tr*128 + pr);
        float pv = keep ? exp2f(acc[mi][ni][i]*SC_EXP) : 0.f;
        ((short*)&pk)[i] = f2bf(pv);
      }
      *(short4*)&Pt[pr*256 + pc0] = pk;
    }
  }
}

// ---------------- kernel 3: O = (P V) / rowsum(P), 128x256 output tiles --------
// Same rolling 3-slot pipeline (72 KiB, one barrier/step, vmcnt(3) steady).
// nst = exact causal extent (tr+1)*4. 512 blocks, 2 rounds pairing tr<->15-tr.
__global__ __launch_bounds__(512,2) void k_pv(const short* __restrict__ Pp,
                                              const short* __restrict__ Vt,
                                              float* __restrict__ out){
  __shared__ short Pl[3][128*32];      // 24 KB
  __shared__ short Vl[3][256*32];      // 48 KB
  const int t = threadIdx.x, l = t & 63, w = t >> 6;
  const int g = l >> 4, c = l & 15;
  int p = blockIdx.x;
  int r = p >> 8, j = p & 255;
  int tr = r ? (15 - (j >> 4)) : (j >> 4);
  int id = r ? (16 + (j & 15)) : (j & 15);     // 32 ids: b(3b) | hc(2b)
  int b = id & 7, hc = id >> 3;                // hc 0..3
  const short* Pb = Pp + ((size_t)(b*72 + (((tr+1)*(tr+1))>>2)))*32768;
  const int wq = w >> 2, wh = w & 3;
  f32x4 acc[4][4] = {};
  float ls[4] = {0.f,0.f,0.f,0.f};

  const int sr = t >> 2, sch = t & 3;
  const int su  = sch ^ ((sr >> 1) & 3);
  const int su2 = sch ^ (((sr + 128) >> 1) & 3);
  const short* Vs0 = Vt + ((size_t)(b*HH + hc*256 + sr))*NN + su*8;
  const short* Vs1 = Vt + ((size_t)(b*HH + hc*256 + sr + 128))*NN + su2*8;
  auto stage = [&](int kt){
    int s = kt % 3;
    const short* Ps = Pb + (size_t)(kt>>3)*32768 + (kt&7)*32;
    GL16(Ps + sr*256 + su*8, (char*)&Pl[s][0] + t*16);
    GL16(Vs0 + kt*32, (char*)&Vl[s][0] + t*16);
    GL16(Vs1 + kt*32, (char*)&Vl[s][0] + 8192 + t*16);
  };

  const int rchunk = (g ^ ((c>>1)&3)) * 8;
  int poff[4], voff[4];
  #pragma unroll
  for (int mi=0;mi<4;mi++) poff[mi] = (wq*64 + mi*16 + c)*32 + rchunk;
  #pragma unroll
  for (int ni=0;ni<4;ni++) voff[ni] = (wh*64 + ni*16 + c)*32 + rchunk;

  auto body = [&](int kt, bool dostage){
    int s = kt % 3;
    __builtin_amdgcn_sched_barrier(0);
    __builtin_amdgcn_s_barrier();
    __builtin_amdgcn_sched_barrier(0);
    s16x8 pf[4], vf[4];
    #pragma unroll
    for (int ni=0;ni<4;ni++) vf[ni] = *(const s16x8*)&Vl[s][voff[ni]];
    #pragma unroll
    for (int mi=0;mi<4;mi++) pf[mi] = *(const s16x8*)&Pl[s][poff[mi]];
    if (dostage) stage(kt+2);
    #pragma unroll
    for (int mi=0;mi<4;mi++){
      #pragma unroll
      for (int e=0;e<8;e++) ls[mi] += bf2f(pf[mi][e]);   // row-sum of P
    }
    __builtin_amdgcn_s_setprio(1);
    #pragma unroll
    for (int mi=0;mi<4;mi++)
      #pragma unroll
      for (int ni=0;ni<4;ni++)
        acc[mi][ni] = MFMA(vf[ni], pf[mi], acc[mi][ni]);
    __builtin_amdgcn_s_setprio(0);
  };

  const int nst = (tr + 1) * 4;                // exact causal extent, >= 4
  stage(0); stage(1);
  for (int kt = 0; kt < nst - 1; ++kt){
    asm volatile("s_waitcnt vmcnt(3)" ::: "memory");
    body(kt, kt + 2 < nst);
  }
  asm volatile("s_waitcnt vmcnt(0)" ::: "memory");
  body(nst - 1, false);

  #pragma unroll
  for (int mi=0;mi<4;mi++){
    ls[mi] += __shfl_xor(ls[mi], 16);
    ls[mi] += __shfl_xor(ls[mi], 32);    // full row-sum; lane row = wq*64+mi*16+c
  }
  #pragma unroll
  for (int mi=0;mi<4;mi++){
    float linv = 1.0f / ls[mi];
    int orow = tr*128 + wq*64 + mi*16 + c;
    #pragma unroll
    for (int ni=0;ni<4;ni++){
      int h0 = hc*256 + wh*64 + ni*16 + g*4;
      float4 o4;
      o4.x = acc[mi][ni][0]*linv; o4.y = acc[mi][ni][1]*linv;
      o4.z = acc[mi][ni][2]*linv; o4.w = acc[mi][ni][3]*linv;
      *(float4*)&out[((size_t)(b*NN + orow))*HH + h0] = o4;
    }
  }
}

extern "C" void kernel_launch(void* const* d_in, const int* in_sizes, int n_in,
                              void* d_out, int out_size, void* d_ws, size_t ws_size,
                              hipStream_t stream) {
  const float* x  = (const float*)d_in[0];
  const float* Wq = (const float*)d_in[1];
  const float* bq = (const float*)d_in[2];
  const float* Wk = (const float*)d_in[3];
  const float* bk = (const float*)d_in[4];
  const float* Wv = (const float*)d_in[5];
  const float* bv = (const float*)d_in[6];
  char* ws = (char*)d_ws;
  // ws layout (bytes). Pp (37.75 MB) OVERLAYS xb+Wt (both dead after k_gemm,
  // and k_s writes Pp only afterwards).
  short* xb = (short*)(ws);                         // 33,554,432
  short* Pp = (short*)(ws);                         // 37,748,736 (overlay)
  short* Wt = (short*)(ws + 33554432u);             //  6,291,456
  short* Qw = (short*)(ws + 41943040u);             // 33,554,432
  short* Kw = (short*)(ws + 75497472u);             // 33,554,432
  short* Vt = (short*)(ws + 109051904u);            // 33,554,432

  k_conv_x<<<8192, 256, 0, stream>>>(x, xb);
  k_conv_w<<<768, 256, 0, stream>>>(Wq, Wk, Wv, Wt);
  k_gemm<<<768, 512, 0, stream>>>(xb, Wt, bq, bk, bv, Qw, Kw, Vt);
  k_s<<<576, 512, 0, stream>>>(Qw, Kw, Pp);
  k_pv<<<512, 512, 0, stream>>>(Pp, Vt, (float*)d_out);
}